// Round 6
// baseline (329.541 us; speedup 1.0000x reference)
//
#include <hip/hip_runtime.h>
#include <stdint.h>
#include <stddef.h>

typedef __bf16 bf16_t;
typedef bf16_t bf16x4 __attribute__((ext_vector_type(4)));
typedef bf16_t bf16x8 __attribute__((ext_vector_type(8)));
typedef float  f32x4  __attribute__((ext_vector_type(4)));
typedef _Float16 f16_t;
typedef f16_t f16x4 __attribute__((ext_vector_type(4)));

#define MFMA_BF16_K32(a, b, c) __builtin_amdgcn_mfma_f32_16x16x32_bf16(a, b, c, 0, 0, 0)
#define MFMA_F16_K16(a, b, c)  __builtin_amdgcn_mfma_f32_16x16x16f16(a, b, c, 0, 0, 0)

// ---------------------------------------------------------------- helpers
__device__ __forceinline__ void gload_lds16(const void* g, void* l) {
    __builtin_amdgcn_global_load_lds(
        (const __attribute__((address_space(1))) void*)g,
        (__attribute__((address_space(3))) void*)l,
        16, 0, 0);
}

// ---------------------------------------------------------------- fused fp32 -> bf16 casts
#define NX 1572864           // x  float4 count
#define NWA 442368           // Wa float4 count
#define NWP 147456           // Wp float4 count
__global__ void cvt_all(const float* __restrict__ x, const float* __restrict__ Wa,
                        const float* __restrict__ Wp, bf16_t* __restrict__ xb,
                        bf16_t* __restrict__ Wab, bf16_t* __restrict__ Wpb) {
    int i = blockIdx.x * blockDim.x + threadIdx.x;
    const float4* src; bf16_t* dst; int j;
    if (i < NX)            { src = (const float4*)x;  dst = xb;  j = i; }
    else if (i < NX + NWA) { src = (const float4*)Wa; dst = Wab; j = i - NX; }
    else                   { src = (const float4*)Wp; dst = Wpb; j = i - NX - NWA; }
    float4 f = src[j];
    bf16x4 o = { (bf16_t)f.x, (bf16_t)f.y, (bf16_t)f.z, (bf16_t)f.w };
    ((bf16x4*)dst)[j] = o;
}

// ---------------------------------------------------------------- GEMM main loop
template <int KDIM>
__device__ __forceinline__ void gemm_mainloop(
    const bf16_t* __restrict__ A, const bf16_t* __restrict__ Bt,
    bf16_t* As, bf16_t* Bs, int m0, int n0, int wave, int lane, f32x4 acc[4][4])
{
    const int quad = lane >> 4, l15 = lane & 15;
    const int wm = ((wave >> 1) << 6), wn = ((wave & 1) << 6);

    const int srow = (wave << 4) + (lane >> 2);                 // 0..63
    const int sw   = (((lane & 3) ^ ((srow >> 1) & 3)) << 3);   // swizzled elem offset
    const bf16_t* gA = A  + (size_t)(m0 + srow) * KDIM + sw;
    const bf16_t* gB = Bt + (size_t)(n0 + srow) * KDIM + sw;
    bf16_t* lA0 = As + wave * 512;
    bf16_t* lA1 = As + 2048 + wave * 512;
    bf16_t* lB0 = Bs + wave * 512;
    bf16_t* lB1 = Bs + 2048 + wave * 512;

    const int xorv = ((quad ^ ((l15 >> 1) & 3)) << 3);

    for (int k0 = 0; k0 < KDIM; k0 += 32) {
        __syncthreads();
        gload_lds16(gA + k0,                       lA0);
        gload_lds16(gA + (size_t)64 * KDIM + k0,   lA1);
        gload_lds16(gB + k0,                       lB0);
        gload_lds16(gB + (size_t)64 * KDIM + k0,   lB1);
        __syncthreads();

        bf16x8 af[4], bfr[4];
#pragma unroll
        for (int t = 0; t < 4; t++) {
            af[t]  = *(const bf16x8*)(As + (wm + t * 16 + l15) * 32 + xorv);
            bfr[t] = *(const bf16x8*)(Bs + (wn + t * 16 + l15) * 32 + xorv);
        }
#pragma unroll
        for (int mt = 0; mt < 4; mt++)
#pragma unroll
            for (int nt = 0; nt < 4; nt++)
                acc[mt][nt] = MFMA_BF16_K32(af[mt], bfr[nt], acc[mt][nt]);
    }
}

// ---------------------------------------------------------------- QKV projection
// qkv[8192,2304] = xb @ W_attn^T + b ; q/k -> bf16 [B,H,T,D], V -> f16 TRANSPOSED [B,H,D,T]
__global__ __launch_bounds__(256) void gemm_qkv(
    const bf16_t* __restrict__ A,   // [8192,768]
    const bf16_t* __restrict__ Bt,  // [2304,768]
    const float* __restrict__ bias, // [2304]
    bf16_t* __restrict__ qo, bf16_t* __restrict__ ko, f16_t* __restrict__ vo)
{
    __shared__ bf16_t As[128 * 32];
    __shared__ bf16_t Bs[128 * 32];
    const int tid = threadIdx.x, wave = tid >> 6, lane = tid & 63;
    const int quad = lane >> 4, l15 = lane & 15;
    const int m0 = blockIdx.y * 128, n0 = blockIdx.x * 128;
    f32x4 acc[4][4] = {};
    gemm_mainloop<768>(A, Bt, As, Bs, m0, n0, wave, lane, acc);

    const int wm = ((wave >> 1) << 6), wn = ((wave & 1) << 6);
#pragma unroll
    for (int nt = 0; nt < 4; nt++) {
        const int cc = n0 + wn + nt * 16 + l15;     // 0..2303
        const float bia = bias[cc];
        const int which = cc / 768;
        const int rem = cc - which * 768;
        const int h = rem >> 6, d = rem & 63;
        if (which < 2) {
            bf16_t* dst = (which == 0) ? qo : ko;
#pragma unroll
            for (int mt = 0; mt < 4; mt++) {
#pragma unroll
                for (int r = 0; r < 4; r++) {
                    const int row = m0 + wm + mt * 16 + quad * 4 + r; // 0..8191
                    const int b = row >> 12, t = row & 4095;
                    dst[((size_t)(b * 12 + h) * 4096 + t) * 64 + d] =
                        (bf16_t)(acc[mt][nt][r] + bia);
                }
            }
        } else {
            // V transposed f16: vo[((b*12+h)*64 + d)*4096 + t]
#pragma unroll
            for (int mt = 0; mt < 4; mt++) {
                const int row0 = m0 + wm + mt * 16 + quad * 4;
                const int b = row0 >> 12, t0 = row0 & 4095;
                f16x4 ov = { (f16_t)(acc[mt][nt][0] + bia),
                             (f16_t)(acc[mt][nt][1] + bia),
                             (f16_t)(acc[mt][nt][2] + bia),
                             (f16_t)(acc[mt][nt][3] + bia) };
                *(f16x4*)(vo + ((size_t)(b * 12 + h) * 64 + d) * 4096 + t0) = ov;
            }
        }
    }
}

// ---------------------------------------------------------------- output projection
__global__ __launch_bounds__(256) void gemm_proj(
    const bf16_t* __restrict__ A,   // y bf16 [8192,768]
    const bf16_t* __restrict__ Bt,  // W_proj bf16 [768,768]
    const float* __restrict__ bias, // [768]
    float* __restrict__ out)        // [8192,768] fp32
{
    __shared__ bf16_t As[128 * 32];
    __shared__ bf16_t Bs[128 * 32];
    const int tid = threadIdx.x, wave = tid >> 6, lane = tid & 63;
    const int quad = lane >> 4, l15 = lane & 15;
    const int m0 = blockIdx.y * 128, n0 = blockIdx.x * 128;
    f32x4 acc[4][4] = {};
    gemm_mainloop<768>(A, Bt, As, Bs, m0, n0, wave, lane, acc);

    const int wm = ((wave >> 1) << 6), wn = ((wave & 1) << 6);
#pragma unroll
    for (int nt = 0; nt < 4; nt++) {
        const int cc = n0 + wn + nt * 16 + l15;
        const float bia = bias[cc];
#pragma unroll
        for (int mt = 0; mt < 4; mt++) {
#pragma unroll
            for (int r = 0; r < 4; r++) {
                const int row = m0 + wm + mt * 16 + quad * 4 + r;
                out[(size_t)row * 768 + cc] = acc[mt][nt][r] + bia;
            }
        }
    }
}

// ---------------------------------------------------------------- flash attention v6
// grid = 1536 (xcd = blk&7 -> 3 heads/XCD for L2 residency; qt = 64 rows).
// 4 waves x 16 q-rows; 64-key tiles double-buffered; LDS 32KB -> 5 blocks/CU
// (occupancy is the round-6 lever: was 2 waves/SIMD, now ~5).
// S^T = K Q^T (C: key=quad*4+r, qrow=l15); P = exp2(S^T) in-register as the
// f16 K16 B-operand; O^T = V^T P. Row sums: per-lane f32 partial (keys of a
// q-row sit at fixed l15 across quads) + 2 shfl_xor in the EPILOGUE — the
// per-tile ones*P MFMAs (59K cyc/CU, 25% of matrix pipe) are gone.
#define QSCALE 0.1803368801f   // log2(e)/8
__global__ __launch_bounds__(256, 5) void attn_fwd(
    const bf16_t* __restrict__ qg, const bf16_t* __restrict__ kg,
    const f16_t* __restrict__ vtg, bf16_t* __restrict__ y) // y [B,T,C] bf16
{
    __shared__ bf16_t Ks0[64 * 64], Ks1[64 * 64];   // [key][dim], chunk-swizzled
    __shared__ f16_t  Vt0[64 * 64], Vt1[64 * 64];   // [dim][key], chunk-swizzled
    const int tid = threadIdx.x, wave = tid >> 6, lane = tid & 63;
    const int quad = lane >> 4, l15 = lane & 15;

    const int blk = blockIdx.x;            // 0..1535
    const int xcd = blk & 7;
    const int idx = blk >> 3;              // 0..191
    const int hl  = idx % 3;
    const int qt  = idx / 3;               // 0..63
    const int bh  = xcd * 3 + hl;          // 0..23
    const int b = bh / 12, h = bh - b * 12;
    const size_t base = (size_t)bh * 4096 * 64;
    const bf16_t* kgt = kg + base;
    const f16_t*  vgt = vtg + base;

    // Q fragment (B-operand layout: n=l15, k=quad*8+j), pre-scaled by log2(e)/8
    const int qrow = qt * 64 + wave * 16 + l15;
    bf16x8 qf[2];
    qf[0] = *(const bf16x8*)(qg + base + (size_t)qrow * 64 + quad * 8);
    qf[1] = *(const bf16x8*)(qg + base + (size_t)qrow * 64 + 32 + quad * 8);
#pragma unroll
    for (int j = 0; j < 8; j++) {
        qf[0][j] = (bf16_t)((float)qf[0][j] * QSCALE);
        qf[1][j] = (bf16_t)((float)qf[1][j] * QSCALE);
    }

    f32x4 O[4] = {};         // O^T[dim][qrow] accumulators
    float psum = 0.f;        // per-lane partial row sum (keys quad*4+r+16ct per tile)

    // staging addresses: 8 lanes cover one 128B row, chunks XOR-permuted on row&7
    const int srow8 = tid >> 3;                  // 0..31 (+32 for i=1)
    const int sc8   = (tid & 7) ^ (srow8 & 7);   // global chunk for slot tid&7
    const int ksoff = (quad ^ (l15 & 7)) << 3;   // K frag slot offset (elems)
    const int l8 = l15 & 7, q1 = quad >> 1, q0off = (quad & 1) * 8;

    auto stage = [&](int kt, bf16_t* Kd, f16_t* Vd) {
        const bf16_t* kp = kgt + (size_t)kt * 64 * 64;
        const f16_t*  vp = vgt + kt * 64;
#pragma unroll
        for (int i = 0; i < 2; i++) {
            gload_lds16(kp + (i * 32 + srow8) * 64 + sc8 * 8,           Kd + (i * 256 + tid) * 8);
            gload_lds16(vp + (size_t)(i * 32 + srow8) * 4096 + sc8 * 8, Vd + (i * 256 + tid) * 8);
        }
    };

    auto compute = [&](const bf16_t* ks, const f16_t* vs) {
        // ---- S^T = K Q^T : C-layout key=16ct+quad*4+r, qrow=l15
        f32x4 sc[4];
#pragma unroll
        for (int ct = 0; ct < 4; ct++) {
            const bf16_t* kr = ks + (ct * 16 + l15) * 64;
            bf16x8 kf0 = *(const bf16x8*)(kr + ksoff);
            bf16x8 kf1 = *(const bf16x8*)(kr + (ksoff ^ 32));
            f32x4 s = {};
            s = MFMA_BF16_K32(kf0, qf[0], s);
            s = MFMA_BF16_K32(kf1, qf[1], s);
            sc[ct] = s;
        }
        // ---- P = exp2(S^T) in-register (K16 B-frag: k=quad*4+r, n=l15);
        //      accumulate per-lane partial row sum in f32
        f16x4 pf[4];
#pragma unroll
        for (int ct = 0; ct < 4; ct++) {
            float e0 = exp2f(sc[ct][0]), e1 = exp2f(sc[ct][1]);
            float e2 = exp2f(sc[ct][2]), e3 = exp2f(sc[ct][3]);
            psum += (e0 + e1) + (e2 + e3);
            f16x4 p = { (f16_t)e0, (f16_t)e1, (f16_t)e2, (f16_t)e3 };
            pf[ct] = p;
        }
        // ---- O^T += V^T P
#pragma unroll
        for (int dt = 0; dt < 4; dt++) {
            const char* vr = (const char*)(vs + (dt * 16 + l15) * 64);
#pragma unroll
            for (int kk = 0; kk < 4; kk++) {
                const int slot = ((kk << 1) | q1) ^ l8;
                f16x4 vf = *(const f16x4*)(vr + slot * 16 + q0off);
                O[dt] = MFMA_F16_K16(vf, pf[kk], O[dt]);
            }
        }
    };

    stage(0, Ks0, Vt0);
    for (int kt = 0; kt < 64; kt += 2) {
        __syncthreads();                 // buf0 loads drained; buf1 readers done
        stage(kt + 1, Ks1, Vt1);         // prefetch overlaps compute below
        compute(Ks0, Vt0);
        __syncthreads();
        if (kt + 2 < 64) stage(kt + 2, Ks0, Vt0);
        compute(Ks1, Vt1);
    }

    // epilogue: row sum = reduce psum over the 4 quads holding this l15 row
    psum += __shfl_xor(psum, 16, 64);
    psum += __shfl_xor(psum, 32, 64);
    const float rcp = 1.0f / psum;
    const int t = qt * 64 + wave * 16 + l15;
    bf16_t* yr = y + ((size_t)b * 4096 + t) * 768 + h * 64 + quad * 4;
#pragma unroll
    for (int dt = 0; dt < 4; dt++) {
        bf16x4 ov = { (bf16_t)(O[dt][0] * rcp), (bf16_t)(O[dt][1] * rcp),
                      (bf16_t)(O[dt][2] * rcp), (bf16_t)(O[dt][3] * rcp) };
        *(bf16x4*)(yr + dt * 16) = ov;
    }
}

// ---------------------------------------------------------------- launch
extern "C" void kernel_launch(void* const* d_in, const int* in_sizes, int n_in,
                              void* d_out, int out_size, void* d_ws, size_t ws_size,
                              hipStream_t stream) {
    const float* x  = (const float*)d_in[0]; // [2,4096,768]
    const float* Wa = (const float*)d_in[1]; // [2304,768]
    const float* ba = (const float*)d_in[2]; // [2304]
    const float* Wp = (const float*)d_in[3]; // [768,768]
    const float* bp = (const float*)d_in[4]; // [768]
    float* out = (float*)d_out;              // [2,4096,768]

    char* ws = (char*)d_ws;
    bf16_t* xb  = (bf16_t*)(ws);                 //  6291456 elts
    bf16_t* Wab = (bf16_t*)(ws + 12582912);      //  1769472
    bf16_t* Wpb = (bf16_t*)(ws + 16121856);      //   589824
    bf16_t* qb  = (bf16_t*)(ws + 17301504);      //  [B,H,T,D] bf16
    bf16_t* kb  = (bf16_t*)(ws + 29884416);      //  [B,H,T,D] bf16
    f16_t*  vtb = (f16_t*)(ws + 42467328);       //  [B,H,D,T] f16 (transposed)
    bf16_t* yb  = (bf16_t*)(ws + 55050240);      //  [B,T,C] bf16

    cvt_all<<<8448, 256, 0, stream>>>(x, Wa, Wp, xb, Wab, Wpb);
    gemm_qkv <<<dim3(18, 64), 256, 0, stream>>>(xb, Wab, ba, qb, kb, vtb);
    attn_fwd <<<1536, 256, 0, stream>>>(qb, kb, vtb, yb);
    gemm_proj<<<dim3( 6, 64), 256, 0, stream>>>(yb, Wpb, bp, out);
}

// Round 7
// 308.782 us; speedup vs baseline: 1.0672x; 1.0672x over previous
//
#include <hip/hip_runtime.h>
#include <stdint.h>
#include <stddef.h>

typedef __bf16 bf16_t;
typedef bf16_t bf16x4 __attribute__((ext_vector_type(4)));
typedef bf16_t bf16x8 __attribute__((ext_vector_type(8)));
typedef float  f32x4  __attribute__((ext_vector_type(4)));
typedef _Float16 f16_t;
typedef f16_t f16x4 __attribute__((ext_vector_type(4)));

#define MFMA_BF16_K32(a, b, c) __builtin_amdgcn_mfma_f32_16x16x32_bf16(a, b, c, 0, 0, 0)
#define MFMA_F16_K16(a, b, c)  __builtin_amdgcn_mfma_f32_16x16x16f16(a, b, c, 0, 0, 0)

// ---------------------------------------------------------------- helpers
__device__ __forceinline__ void gload_lds16(const void* g, void* l) {
    __builtin_amdgcn_global_load_lds(
        (const __attribute__((address_space(1))) void*)g,
        (__attribute__((address_space(3))) void*)l,
        16, 0, 0);
}

// ---------------------------------------------------------------- fused fp32 -> bf16 casts
#define NX 1572864           // x  float4 count
#define NWA 442368           // Wa float4 count
#define NWP 147456           // Wp float4 count
__global__ void cvt_all(const float* __restrict__ x, const float* __restrict__ Wa,
                        const float* __restrict__ Wp, bf16_t* __restrict__ xb,
                        bf16_t* __restrict__ Wab, bf16_t* __restrict__ Wpb) {
    int i = blockIdx.x * blockDim.x + threadIdx.x;
    const float4* src; bf16_t* dst; int j;
    if (i < NX)            { src = (const float4*)x;  dst = xb;  j = i; }
    else if (i < NX + NWA) { src = (const float4*)Wa; dst = Wab; j = i - NX; }
    else                   { src = (const float4*)Wp; dst = Wpb; j = i - NX - NWA; }
    float4 f = src[j];
    bf16x4 o = { (bf16_t)f.x, (bf16_t)f.y, (bf16_t)f.z, (bf16_t)f.w };
    ((bf16x4*)dst)[j] = o;
}

// ---------------------------------------------------------------- GEMM main loop
template <int KDIM>
__device__ __forceinline__ void gemm_mainloop(
    const bf16_t* __restrict__ A, const bf16_t* __restrict__ Bt,
    bf16_t* As, bf16_t* Bs, int m0, int n0, int wave, int lane, f32x4 acc[4][4])
{
    const int quad = lane >> 4, l15 = lane & 15;
    const int wm = ((wave >> 1) << 6), wn = ((wave & 1) << 6);

    const int srow = (wave << 4) + (lane >> 2);                 // 0..63
    const int sw   = (((lane & 3) ^ ((srow >> 1) & 3)) << 3);   // swizzled elem offset
    const bf16_t* gA = A  + (size_t)(m0 + srow) * KDIM + sw;
    const bf16_t* gB = Bt + (size_t)(n0 + srow) * KDIM + sw;
    bf16_t* lA0 = As + wave * 512;
    bf16_t* lA1 = As + 2048 + wave * 512;
    bf16_t* lB0 = Bs + wave * 512;
    bf16_t* lB1 = Bs + 2048 + wave * 512;

    const int xorv = ((quad ^ ((l15 >> 1) & 3)) << 3);

    for (int k0 = 0; k0 < KDIM; k0 += 32) {
        __syncthreads();
        gload_lds16(gA + k0,                       lA0);
        gload_lds16(gA + (size_t)64 * KDIM + k0,   lA1);
        gload_lds16(gB + k0,                       lB0);
        gload_lds16(gB + (size_t)64 * KDIM + k0,   lB1);
        __syncthreads();

        bf16x8 af[4], bfr[4];
#pragma unroll
        for (int t = 0; t < 4; t++) {
            af[t]  = *(const bf16x8*)(As + (wm + t * 16 + l15) * 32 + xorv);
            bfr[t] = *(const bf16x8*)(Bs + (wn + t * 16 + l15) * 32 + xorv);
        }
#pragma unroll
        for (int mt = 0; mt < 4; mt++)
#pragma unroll
            for (int nt = 0; nt < 4; nt++)
                acc[mt][nt] = MFMA_BF16_K32(af[mt], bfr[nt], acc[mt][nt]);
    }
}

// ---------------------------------------------------------------- QKV projection
__global__ __launch_bounds__(256) void gemm_qkv(
    const bf16_t* __restrict__ A,   // [8192,768]
    const bf16_t* __restrict__ Bt,  // [2304,768]
    const float* __restrict__ bias, // [2304]
    bf16_t* __restrict__ qo, bf16_t* __restrict__ ko, f16_t* __restrict__ vo)
{
    __shared__ bf16_t As[128 * 32];
    __shared__ bf16_t Bs[128 * 32];
    const int tid = threadIdx.x, wave = tid >> 6, lane = tid & 63;
    const int quad = lane >> 4, l15 = lane & 15;
    const int m0 = blockIdx.y * 128, n0 = blockIdx.x * 128;
    f32x4 acc[4][4] = {};
    gemm_mainloop<768>(A, Bt, As, Bs, m0, n0, wave, lane, acc);

    const int wm = ((wave >> 1) << 6), wn = ((wave & 1) << 6);
#pragma unroll
    for (int nt = 0; nt < 4; nt++) {
        const int cc = n0 + wn + nt * 16 + l15;     // 0..2303
        const float bia = bias[cc];
        const int which = cc / 768;
        const int rem = cc - which * 768;
        const int h = rem >> 6, d = rem & 63;
        if (which < 2) {
            bf16_t* dst = (which == 0) ? qo : ko;
#pragma unroll
            for (int mt = 0; mt < 4; mt++) {
#pragma unroll
                for (int r = 0; r < 4; r++) {
                    const int row = m0 + wm + mt * 16 + quad * 4 + r; // 0..8191
                    const int b = row >> 12, t = row & 4095;
                    dst[((size_t)(b * 12 + h) * 4096 + t) * 64 + d] =
                        (bf16_t)(acc[mt][nt][r] + bia);
                }
            }
        } else {
            // V transposed f16: vo[((b*12+h)*64 + d)*4096 + t]
#pragma unroll
            for (int mt = 0; mt < 4; mt++) {
                const int row0 = m0 + wm + mt * 16 + quad * 4;
                const int b = row0 >> 12, t0 = row0 & 4095;
                f16x4 ov = { (f16_t)(acc[mt][nt][0] + bia),
                             (f16_t)(acc[mt][nt][1] + bia),
                             (f16_t)(acc[mt][nt][2] + bia),
                             (f16_t)(acc[mt][nt][3] + bia) };
                *(f16x4*)(vo + ((size_t)(b * 12 + h) * 64 + d) * 4096 + t0) = ov;
            }
        }
    }
}

// ---------------------------------------------------------------- output projection
__global__ __launch_bounds__(256) void gemm_proj(
    const bf16_t* __restrict__ A,   // y bf16 [8192,768]
    const bf16_t* __restrict__ Bt,  // W_proj bf16 [768,768]
    const float* __restrict__ bias, // [768]
    float* __restrict__ out)        // [8192,768] fp32
{
    __shared__ bf16_t As[128 * 32];
    __shared__ bf16_t Bs[128 * 32];
    const int tid = threadIdx.x, wave = tid >> 6, lane = tid & 63;
    const int quad = lane >> 4, l15 = lane & 15;
    const int m0 = blockIdx.y * 128, n0 = blockIdx.x * 128;
    f32x4 acc[4][4] = {};
    gemm_mainloop<768>(A, Bt, As, Bs, m0, n0, wave, lane, acc);

    const int wm = ((wave >> 1) << 6), wn = ((wave & 1) << 6);
#pragma unroll
    for (int nt = 0; nt < 4; nt++) {
        const int cc = n0 + wn + nt * 16 + l15;
        const float bia = bias[cc];
#pragma unroll
        for (int mt = 0; mt < 4; mt++) {
#pragma unroll
            for (int r = 0; r < 4; r++) {
                const int row = m0 + wm + mt * 16 + quad * 4 + r;
                out[(size_t)row * 768 + cc] = acc[mt][nt][r] + bia;
            }
        }
    }
}

// ---------------------------------------------------------------- flash attention v7
// KEY-SPLIT: wave w owns keys [w*16, w*16+16) of every 64-key tile, for ALL 64
// q-rows of the block (Q held in regs). Each staged K/V element is read by
// exactly ONE wave -> per-tile LDS traffic 80KB -> 32KB; V-reads/wave-tile
// 16 -> 4. O partials are additive (no-max softmax) and reduced across waves
// once, in an LDS epilogue overlaying the staging buffers.
// S^T = K Q^T per 16-qrow chunk (C: key=quad*4+r, qrow=l15); P = exp2 in-reg
// as f16 K16 operands; O^T = V^T P (C: dim=quad*4+r, qrow=l15).
#define QSCALE 0.1803368801f   // log2(e)/8
__global__ __launch_bounds__(256, 3) void attn_fwd(
    const bf16_t* __restrict__ qg, const bf16_t* __restrict__ kg,
    const f16_t* __restrict__ vtg, bf16_t* __restrict__ y) // y [B,T,C] bf16
{
    __shared__ __align__(16) char smem[36608];
    bf16_t* Ks0 = (bf16_t*)(smem);              // 8KB [key][dim] swizzled
    bf16_t* Ks1 = (bf16_t*)(smem + 8192);
    f16_t*  Vt0 = (f16_t*)(smem + 16384);       // 8KB [dim][key] swizzled
    f16_t*  Vt1 = (f16_t*)(smem + 24576);
    float*  RedA = (float*)(smem);              // epilogue overlays (stride 68)
    float*  RedB = (float*)(smem + 17408);
    float*  Psr  = (float*)(smem + 34816);      // [4][64]
    float*  PsT  = (float*)(smem + 35840);      // [64]

    const int tid = threadIdx.x, wave = tid >> 6, lane = tid & 63;
    const int quad = lane >> 4, l15 = lane & 15;

    const int blk = blockIdx.x;            // 0..1535
    const int xcd = blk & 7;
    const int idx = blk >> 3;              // 0..191
    const int hl  = idx % 3;
    const int qt  = idx / 3;               // 0..63
    const int bh  = xcd * 3 + hl;          // 0..23
    const int b = bh / 12, h = bh - b * 12;
    const size_t base = (size_t)bh * 4096 * 64;
    const bf16_t* kgt = kg + base;
    const f16_t*  vgt = vtg + base;

    // Q fragments for ALL 4 qrow-chunks (B-operand: n=l15, k=quad*8+j), *log2e/8
    bf16x8 qf[4][2];
#pragma unroll
    for (int qc = 0; qc < 4; qc++) {
        const int qrow = qt * 64 + qc * 16 + l15;
        qf[qc][0] = *(const bf16x8*)(qg + base + (size_t)qrow * 64 + quad * 8);
        qf[qc][1] = *(const bf16x8*)(qg + base + (size_t)qrow * 64 + 32 + quad * 8);
#pragma unroll
        for (int j = 0; j < 8; j++) {
            qf[qc][0][j] = (bf16_t)((float)qf[qc][0][j] * QSCALE);
            qf[qc][1][j] = (bf16_t)((float)qf[qc][1][j] * QSCALE);
        }
    }

    f32x4 O[4][4] = {};      // O^T partial: [dt][qc], elem r: dim=dt*16+quad*4+r, qrow=qc*16+l15
    float psum[4] = {};      // per-lane partial row sums (qrow = qc*16+l15)

    // staging: 8 lanes per 128B row, 16B chunks XOR-swizzled on row&7
    const int srow8 = tid >> 3;                  // 0..31 (+32 for i=1)
    const int sc8   = (tid & 7) ^ (srow8 & 7);
    const int l8 = l15 & 7;
    const int w16 = wave << 4;
    const int ksoff = (quad ^ l8) << 3;                          // K frag slot (elems)
    const int vslot = ((wave << 1) | (quad >> 1)) ^ l8;          // V frag 16B slot
    const int q0off = (quad & 1) * 8;

    auto stage = [&](int kt, bf16_t* Kd, f16_t* Vd) {
        const bf16_t* kp = kgt + (size_t)kt * 64 * 64;
        const f16_t*  vp = vgt + kt * 64;
#pragma unroll
        for (int i = 0; i < 2; i++) {
            gload_lds16(kp + (i * 32 + srow8) * 64 + sc8 * 8,           Kd + (i * 256 + tid) * 8);
            gload_lds16(vp + (size_t)(i * 32 + srow8) * 4096 + sc8 * 8, Vd + (i * 256 + tid) * 8);
        }
    };

    auto compute = [&](const bf16_t* ks, const f16_t* vs) {
        // ---- S^T (wave's 16 keys x 64 qrows): 2 LDS reads feed 8 MFMAs
        const bf16_t* kr = ks + (w16 + l15) * 64;
        bf16x8 kf0 = *(const bf16x8*)(kr + ksoff);
        bf16x8 kf1 = *(const bf16x8*)(kr + (ksoff ^ 32));
        f32x4 sc[4];
#pragma unroll
        for (int qc = 0; qc < 4; qc++) {
            f32x4 s = {};
            s = MFMA_BF16_K32(kf0, qf[qc][0], s);
            s = MFMA_BF16_K32(kf1, qf[qc][1], s);
            sc[qc] = s;
        }
        // ---- P = exp2(S^T) in-register (key=quad*4+r, qrow=l15)
        f16x4 pf[4];
#pragma unroll
        for (int qc = 0; qc < 4; qc++) {
            float e0 = exp2f(sc[qc][0]), e1 = exp2f(sc[qc][1]);
            float e2 = exp2f(sc[qc][2]), e3 = exp2f(sc[qc][3]);
            psum[qc] += (e0 + e1) + (e2 + e3);
            f16x4 p = { (f16_t)e0, (f16_t)e1, (f16_t)e2, (f16_t)e3 };
            pf[qc] = p;
        }
        // ---- O^T += V^T P : 4 LDS b64 reads feed 16 MFMAs
#pragma unroll
        for (int dt = 0; dt < 4; dt++) {
            const char* vr = (const char*)(vs + (dt * 16 + l15) * 64);
            f16x4 vf = *(const f16x4*)(vr + vslot * 16 + q0off);
#pragma unroll
            for (int qc = 0; qc < 4; qc++)
                O[dt][qc] = MFMA_F16_K16(vf, pf[qc], O[dt][qc]);
        }
    };

    stage(0, Ks0, Vt0);
    for (int kt = 0; kt < 64; kt += 2) {
        __syncthreads();                 // buf0 loads drained; buf1 readers done
        stage(kt + 1, Ks1, Vt1);         // prefetch overlaps compute below
        compute(Ks0, Vt0);
        __syncthreads();
        if (kt + 2 < 64) stage(kt + 2, Ks0, Vt0);
        compute(Ks1, Vt1);
    }

    // ================= epilogue: reduce O & psum across the 4 key-split waves
#pragma unroll
    for (int qc = 0; qc < 4; qc++) {
        psum[qc] += __shfl_xor(psum[qc], 16, 64);
        psum[qc] += __shfl_xor(psum[qc], 32, 64);
    }
    __syncthreads();   // S1: K-loop LDS quiesced; overlay safe
    if (wave == 2) {
#pragma unroll
        for (int dt = 0; dt < 4; dt++)
#pragma unroll
            for (int qc = 0; qc < 4; qc++)
                *(f32x4*)(RedA + (qc * 16 + l15) * 68 + dt * 16 + quad * 4) = O[dt][qc];
    } else if (wave == 3) {
#pragma unroll
        for (int dt = 0; dt < 4; dt++)
#pragma unroll
            for (int qc = 0; qc < 4; qc++)
                *(f32x4*)(RedB + (qc * 16 + l15) * 68 + dt * 16 + quad * 4) = O[dt][qc];
    }
    if (quad == 0) {
#pragma unroll
        for (int qc = 0; qc < 4; qc++) Psr[wave * 64 + qc * 16 + l15] = psum[qc];
    }
    __syncthreads();   // S2
    if (wave == 0) {
#pragma unroll
        for (int dt = 0; dt < 4; dt++)
#pragma unroll
            for (int qc = 0; qc < 4; qc++)
                O[dt][qc] += *(const f32x4*)(RedA + (qc * 16 + l15) * 68 + dt * 16 + quad * 4);
    } else if (wave == 1) {
#pragma unroll
        for (int dt = 0; dt < 4; dt++)
#pragma unroll
            for (int qc = 0; qc < 4; qc++)
                O[dt][qc] += *(const f32x4*)(RedB + (qc * 16 + l15) * 68 + dt * 16 + quad * 4);
    }
    __syncthreads();   // S3
    if (wave == 1) {
#pragma unroll
        for (int dt = 0; dt < 4; dt++)
#pragma unroll
            for (int qc = 0; qc < 4; qc++)
                *(f32x4*)(RedA + (qc * 16 + l15) * 68 + dt * 16 + quad * 4) = O[dt][qc];
    } else if (wave == 3) {
        PsT[lane] = Psr[lane] + Psr[64 + lane] + Psr[128 + lane] + Psr[192 + lane];
    }
    __syncthreads();   // S4
    if (wave == 0) {
#pragma unroll
        for (int qc = 0; qc < 4; qc++) {
            const float rcp = 1.0f / PsT[qc * 16 + l15];
            const int t = qt * 64 + qc * 16 + l15;
            bf16_t* yr = y + ((size_t)b * 4096 + t) * 768 + h * 64 + quad * 4;
#pragma unroll
            for (int dt = 0; dt < 4; dt++) {
                f32x4 o4 = O[dt][qc] +
                    *(const f32x4*)(RedA + (qc * 16 + l15) * 68 + dt * 16 + quad * 4);
                bf16x4 ov = { (bf16_t)(o4[0] * rcp), (bf16_t)(o4[1] * rcp),
                              (bf16_t)(o4[2] * rcp), (bf16_t)(o4[3] * rcp) };
                *(bf16x4*)(yr + dt * 16) = ov;
            }
        }
    }
}

// ---------------------------------------------------------------- launch
extern "C" void kernel_launch(void* const* d_in, const int* in_sizes, int n_in,
                              void* d_out, int out_size, void* d_ws, size_t ws_size,
                              hipStream_t stream) {
    const float* x  = (const float*)d_in[0]; // [2,4096,768]
    const float* Wa = (const float*)d_in[1]; // [2304,768]
    const float* ba = (const float*)d_in[2]; // [2304]
    const float* Wp = (const float*)d_in[3]; // [768,768]
    const float* bp = (const float*)d_in[4]; // [768]
    float* out = (float*)d_out;              // [2,4096,768]

    char* ws = (char*)d_ws;
    bf16_t* xb  = (bf16_t*)(ws);                 //  6291456 elts
    bf16_t* Wab = (bf16_t*)(ws + 12582912);      //  1769472
    bf16_t* Wpb = (bf16_t*)(ws + 16121856);      //   589824
    bf16_t* qb  = (bf16_t*)(ws + 17301504);      //  [B,H,T,D] bf16
    bf16_t* kb  = (bf16_t*)(ws + 29884416);      //  [B,H,T,D] bf16
    f16_t*  vtb = (f16_t*)(ws + 42467328);       //  [B,H,D,T] f16 (transposed)
    bf16_t* yb  = (bf16_t*)(ws + 55050240);      //  [B,T,C] bf16

    cvt_all<<<8448, 256, 0, stream>>>(x, Wa, Wp, xb, Wab, Wpb);
    gemm_qkv <<<dim3(18, 64), 256, 0, stream>>>(xb, Wab, ba, qb, kb, vtb);
    attn_fwd <<<1536, 256, 0, stream>>>(qb, kb, vtb, yb);
    gemm_proj<<<dim3( 6, 64), 256, 0, stream>>>(yb, Wpb, bp, out);
}